// Round 1
// baseline (776.846 us; speedup 1.0000x reference)
//
#include <hip/hip_runtime.h>
#include <math.h>

#define N_NODES 30000
#define N_EDGES 480000
#define HEADS 4
#define DHEAD 64
#define FDIM 256   // HEADS * DHEAD
#define POSD 32

__device__ __forceinline__ float wave_red_sum(float v){
#pragma unroll
  for (int o = 32; o > 0; o >>= 1) v += __shfl_xor(v, o, 64);
  return v;
}
__device__ __forceinline__ float wave_red_max(float v){
#pragma unroll
  for (int o = 32; o > 0; o >>= 1) v = fmaxf(v, __shfl_xor(v, o, 64));
  return v;
}

// ---------------- CSR build ----------------
__global__ void hist_k(const int* __restrict__ dst, int* __restrict__ deg){
  int e = blockIdx.x * blockDim.x + threadIdx.x;
  if (e < N_EDGES) atomicAdd(&deg[dst[e]], 1);
}

// single-block exclusive scan over deg[0..N) -> off, cursor; off[N]=E
__global__ void scan_k(const int* __restrict__ deg, int* __restrict__ off,
                       int* __restrict__ cursor){
  __shared__ int sm[1024];
  __shared__ int carry_s;
  int t = threadIdx.x;
  if (t == 0) carry_s = 0;
  __syncthreads();
  for (int base = 0; base < N_NODES; base += 1024){
    int i = base + t;
    int x = (i < N_NODES) ? deg[i] : 0;
    sm[t] = x;
    __syncthreads();
#pragma unroll
    for (int o = 1; o < 1024; o <<= 1){
      int v = (t >= o) ? sm[t - o] : 0;
      __syncthreads();
      sm[t] += v;
      __syncthreads();
    }
    int incl = sm[t];
    int excl = incl - x + carry_s;
    if (i < N_NODES){ off[i] = excl; cursor[i] = excl; }
    __syncthreads();
    if (t == 1023) carry_s += incl;
    __syncthreads();
  }
  if (t == 0) off[N_NODES] = N_EDGES;
}

__global__ void scatter_k(const int* __restrict__ src, const int* __restrict__ dst,
                          int* __restrict__ cursor, int* __restrict__ esrc){
  int e = blockIdx.x * blockDim.x + threadIdx.x;
  if (e < N_EDGES){
    int d = dst[e];
    int p = atomicAdd(&cursor[d], 1);
    esrc[p] = src[e];
  }
}

// ---------------- pe[pos] @ W_tail bias table: PW[v][j] ----------------
__global__ void pw_k(const float* __restrict__ W, const float* __restrict__ pe,
                     float* __restrict__ PW, int K){
  int v = blockIdx.x;       // 0..2
  int j = threadIdx.x;      // 0..255
  float s = 0.f;
#pragma unroll
  for (int k = 0; k < POSD; k++)
    s = fmaf(pe[v * POSD + k], W[(size_t)(K + k) * FDIM + j], s);
  PW[v * FDIM + j] = s;
}

// ---------------- GEMM: C[N,256] = A[N,K] @ W[0:K,0:256] + PW[pos[n]] ----------------
// 64x64 tile, BK=16, 256 threads, 4x4 micro-tile
__global__ __launch_bounds__(256) void gemm_k(
    const float* __restrict__ A, const float* __restrict__ W,
    const float* __restrict__ PW, const int* __restrict__ pos,
    float* __restrict__ C, int K){
  __shared__ float As[16][68];   // [k][m], +4 pad
  __shared__ float Bs[16][64];   // [k][n]
  int t  = threadIdx.x;
  int tx = t & 15, ty = t >> 4;
  int rowBase = blockIdx.y * 64;
  int colBase = blockIdx.x * 64;
  float acc[4][4] = {{0.f}};
  int ar  = t >> 2, ac4 = t & 3;   // A stage: row ar, k-float4 group ac4
  int bk  = t >> 4, bj  = t & 15;  // B stage: k row bk, col-float4 group bj

  for (int kb = 0; kb < K; kb += 16){
    int arow = rowBase + ar;
    float4 av = make_float4(0.f, 0.f, 0.f, 0.f);
    if (arow < N_NODES)
      av = *(const float4*)&A[(size_t)arow * K + kb + ac4 * 4];
    As[ac4 * 4 + 0][ar] = av.x;
    As[ac4 * 4 + 1][ar] = av.y;
    As[ac4 * 4 + 2][ar] = av.z;
    As[ac4 * 4 + 3][ar] = av.w;
    *(float4*)&Bs[bk][bj * 4] =
        *(const float4*)&W[(size_t)(kb + bk) * FDIM + colBase + bj * 4];
    __syncthreads();
#pragma unroll
    for (int kk = 0; kk < 16; kk++){
      float4 a = *(const float4*)&As[kk][ty * 4];
      float4 b = *(const float4*)&Bs[kk][tx * 4];
      float aa[4] = {a.x, a.y, a.z, a.w};
      float bb[4] = {b.x, b.y, b.z, b.w};
#pragma unroll
      for (int i = 0; i < 4; i++)
#pragma unroll
        for (int j = 0; j < 4; j++)
          acc[i][j] = fmaf(aa[i], bb[j], acc[i][j]);
    }
    __syncthreads();
  }
#pragma unroll
  for (int i = 0; i < 4; i++){
    int row = rowBase + ty * 4 + i;
    if (row < N_NODES){
      int p = pos[row];
      const float* pw = &PW[p * FDIM + colBase + tx * 4];
      float4 o;
      o.x = acc[i][0] + pw[0];
      o.y = acc[i][1] + pw[1];
      o.z = acc[i][2] + pw[2];
      o.w = acc[i][3] + pw[3];
      *(float4*)&C[(size_t)row * FDIM + colBase + tx * 4] = o;
    }
  }
}

// ---------------- attention coefficients a1[n,h], a2[n,h] ----------------
__global__ void attn_k(const float* __restrict__ ft, const float* __restrict__ al,
                       const float* __restrict__ arr, float* __restrict__ a1,
                       float* __restrict__ a2){
  int n = blockIdx.x;
  int t = threadIdx.x;
  int h = t >> 6, l = t & 63;
  float f = ft[(size_t)n * FDIM + t];
  float s1 = wave_red_sum(f * al[h * DHEAD + l]);
  float s2 = wave_red_sum(f * arr[h * DHEAD + l]);
  if (l == 0){
    a1[n * HEADS + h] = s1;
    a2[n * HEADS + h] = s2;
  }
}

// ---------------- per-dst softmax + aggregate (+ ELU or head-mean) ----------------
// one block per node; wave = head, lane = dim
__global__ __launch_bounds__(256) void agg_k(
    const float* __restrict__ ft, const float* __restrict__ a1,
    const float* __restrict__ a2, const int* __restrict__ off,
    const int* __restrict__ esrc, float* __restrict__ out, int mode){
  __shared__ float red[HEADS][DHEAD];
  int n = blockIdx.x;
  int t = threadIdx.x;
  int h = t >> 6, l = t & 63;
  int jb = off[n], je = off[n + 1];
  float a2n = a2[n * HEADS + h];

  // pass 1: segment max (lane-strided)
  float m = -INFINITY;
  for (int j = jb + l; j < je; j += 64){
    int s = esrc[j];
    float e = a1[s * HEADS + h] + a2n;
    e = e > 0.f ? e : 0.2f * e;
    m = fmaxf(m, e);
  }
  m = wave_red_max(m);

  // pass 2: sum exp
  float ssum = 0.f;
  for (int j = jb + l; j < je; j += 64){
    int s = esrc[j];
    float e = a1[s * HEADS + h] + a2n;
    e = e > 0.f ? e : 0.2f * e;
    ssum += __expf(e - m);
  }
  ssum = wave_red_sum(ssum);
  float inv = (ssum > 0.f) ? 1.f / ssum : 0.f;

  // pass 3: weighted feature gather (all lanes walk all edges; lane = dim)
  float acc = 0.f;
  for (int j = jb; j < je; j++){
    int s = esrc[j];
    float e = a1[s * HEADS + h] + a2n;
    e = e > 0.f ? e : 0.2f * e;
    float wgt = __expf(e - m) * inv;
    acc = fmaf(wgt, ft[(size_t)s * FDIM + h * DHEAD + l], acc);
  }

  if (mode == 0){
    float r = acc > 0.f ? acc : (__expf(acc * 1.4426950408889634f) - 1.f); // careful: see below
    // NOTE: __expf computes 2^x semantics only via v_exp; HIP __expf(x)=e^x. Use plain form:
    r = acc > 0.f ? acc : (__expf(acc) - 1.f);
    out[(size_t)n * FDIM + h * DHEAD + l] = r;
  } else {
    red[h][l] = acc;
    __syncthreads();
    if (h == 0){
      float r = (red[0][l] + red[1][l] + red[2][l] + red[3][l]) * 0.25f;
      out[(size_t)n * DHEAD + l] = r;
    }
  }
}

// ---------------- launch ----------------
extern "C" void kernel_launch(void* const* d_in, const int* in_sizes, int n_in,
                              void* d_out, int out_size, void* d_ws, size_t ws_size,
                              hipStream_t stream){
  const float* features = (const float*)d_in[0];
  const float* W0  = (const float*)d_in[1];
  const float* al0 = (const float*)d_in[2];
  const float* ar0 = (const float*)d_in[3];
  const float* pe0 = (const float*)d_in[4];
  const float* W1  = (const float*)d_in[5];
  const float* al1 = (const float*)d_in[6];
  const float* ar1 = (const float*)d_in[7];
  const float* pe1 = (const float*)d_in[8];
  const float* W2  = (const float*)d_in[9];
  const float* al2 = (const float*)d_in[10];
  const float* ar2 = (const float*)d_in[11];
  const float* pe2 = (const float*)d_in[12];
  const int* srcv  = (const int*)d_in[13];
  const int* dstv  = (const int*)d_in[14];
  const int* posv  = (const int*)d_in[15];
  float* out = (float*)d_out;

  char* wp = (char*)d_ws;
  auto alloc = [&](size_t bytes){
    void* p = (void*)wp;
    wp += (bytes + 255) & ~(size_t)255;
    return p;
  };
  float* ft     = (float*)alloc(sizeof(float) * (size_t)N_NODES * FDIM);
  float* hbuf   = (float*)alloc(sizeof(float) * (size_t)N_NODES * FDIM);
  float* a1     = (float*)alloc(sizeof(float) * N_NODES * HEADS);
  float* a2     = (float*)alloc(sizeof(float) * N_NODES * HEADS);
  float* PW     = (float*)alloc(sizeof(float) * 3 * FDIM);
  int*   deg    = (int*)alloc(sizeof(int) * N_NODES);
  int*   off    = (int*)alloc(sizeof(int) * (N_NODES + 1));
  int*   cursor = (int*)alloc(sizeof(int) * N_NODES);
  int*   esrc   = (int*)alloc(sizeof(int) * N_EDGES);

  // CSR build (graph is identical for all 3 layers)
  hipMemsetAsync(deg, 0, sizeof(int) * N_NODES, stream);
  hist_k<<<(N_EDGES + 255) / 256, 256, 0, stream>>>(dstv, deg);
  scan_k<<<1, 1024, 0, stream>>>(deg, off, cursor);
  scatter_k<<<(N_EDGES + 255) / 256, 256, 0, stream>>>(srcv, dstv, cursor, esrc);

  dim3 ggrid(4, (N_NODES + 63) / 64);

  // layer 0 (K=128, input = features)
  pw_k<<<3, 256, 0, stream>>>(W0, pe0, PW, 128);
  gemm_k<<<ggrid, 256, 0, stream>>>(features, W0, PW, posv, ft, 128);
  attn_k<<<N_NODES, 256, 0, stream>>>(ft, al0, ar0, a1, a2);
  agg_k<<<N_NODES, 256, 0, stream>>>(ft, a1, a2, off, esrc, hbuf, 0);

  // layer 1 (K=256)
  pw_k<<<3, 256, 0, stream>>>(W1, pe1, PW, 256);
  gemm_k<<<ggrid, 256, 0, stream>>>(hbuf, W1, PW, posv, ft, 256);
  attn_k<<<N_NODES, 256, 0, stream>>>(ft, al1, ar1, a1, a2);
  agg_k<<<N_NODES, 256, 0, stream>>>(ft, a1, a2, off, esrc, hbuf, 0);

  // layer 2 (K=256, head-mean -> d_out)
  pw_k<<<3, 256, 0, stream>>>(W2, pe2, PW, 256);
  gemm_k<<<ggrid, 256, 0, stream>>>(hbuf, W2, PW, posv, ft, 256);
  attn_k<<<N_NODES, 256, 0, stream>>>(ft, al2, ar2, a1, a2);
  agg_k<<<N_NODES, 256, 0, stream>>>(ft, a1, a2, off, esrc, out, 1);
}

// Round 3
// 576.634 us; speedup vs baseline: 1.3472x; 1.3472x over previous
//
#include <hip/hip_runtime.h>
#include <math.h>

#define N_NODES 30000
#define N_EDGES 480000
#define HEADS 4
#define DHEAD 64
#define FDIM 256   // HEADS * DHEAD
#define POSD 32
#define SCAN_B 1024
#define SCAN_NB ((N_NODES + SCAN_B - 1) / SCAN_B)   // 30

__device__ __forceinline__ float wave_red_sum(float v){
#pragma unroll
  for (int o = 32; o > 0; o >>= 1) v += __shfl_xor(v, o, 64);
  return v;
}
__device__ __forceinline__ float wave_red_max(float v){
#pragma unroll
  for (int o = 32; o > 0; o >>= 1) v = fmaxf(v, __shfl_xor(v, o, 64));
  return v;
}
__device__ __forceinline__ float lrelu(float x){ return x > 0.f ? x : 0.2f * x; }

// ---------------- CSR build ----------------
__global__ void hist_k(const int* __restrict__ dst, int* __restrict__ deg){
  int e = blockIdx.x * blockDim.x + threadIdx.x;
  if (e < N_EDGES) atomicAdd(&deg[dst[e]], 1);
}

// per-block exclusive scan (1024 elems/block), block totals -> bsum
__global__ void scanA_k(const int* __restrict__ deg, int* __restrict__ off,
                        int* __restrict__ bsum){
  __shared__ int sm[SCAN_B];
  int t = threadIdx.x;
  int i = blockIdx.x * SCAN_B + t;
  int x = (i < N_NODES) ? deg[i] : 0;
  sm[t] = x;
  __syncthreads();
#pragma unroll
  for (int o = 1; o < SCAN_B; o <<= 1){
    int v = (t >= o) ? sm[t - o] : 0;
    __syncthreads();
    sm[t] += v;
    __syncthreads();
  }
  if (i < N_NODES) off[i] = sm[t] - x;
  if (t == SCAN_B - 1) bsum[blockIdx.x] = sm[t];
}

// scan the 30 block sums
__global__ void scanB_k(int* __restrict__ bsum, int* __restrict__ boff){
  __shared__ int sm[64];
  int t = threadIdx.x;
  int x = (t < SCAN_NB) ? bsum[t] : 0;
  sm[t] = x;
  __syncthreads();
#pragma unroll
  for (int o = 1; o < 64; o <<= 1){
    int v = (t >= o) ? sm[t - o] : 0;
    __syncthreads();
    sm[t] += v;
    __syncthreads();
  }
  if (t < SCAN_NB) boff[t] = sm[t] - x;
}

__global__ void scanC_k(int* __restrict__ off, const int* __restrict__ boff,
                        int* __restrict__ cursor){
  int i = blockIdx.x * SCAN_B + threadIdx.x;
  if (i < N_NODES){
    int v = off[i] + boff[blockIdx.x];
    off[i] = v;
    cursor[i] = v;
  }
  if (i == 0) off[N_NODES] = N_EDGES;
}

__global__ void scatter_k(const int* __restrict__ src, const int* __restrict__ dst,
                          int* __restrict__ cursor, int* __restrict__ esrc){
  int e = blockIdx.x * blockDim.x + threadIdx.x;
  if (e < N_EDGES){
    int d = dst[e];
    int p = atomicAdd(&cursor[d], 1);
    esrc[p] = src[e];
  }
}

// ---------------- pe[pos] @ W_tail bias table: PW[v][j] ----------------
__global__ void pw_k(const float* __restrict__ W, const float* __restrict__ pe,
                     float* __restrict__ PW, int K){
  int v = blockIdx.x;       // 0..2
  int j = threadIdx.x;      // 0..255
  float s = 0.f;
#pragma unroll
  for (int k = 0; k < POSD; k++)
    s = fmaf(pe[v * POSD + k], W[(size_t)(K + k) * FDIM + j], s);
  PW[v * FDIM + j] = s;
}

// ---------------- GEMM + fused attention coefficients ----------------
// C[N,256] = A[N,K] @ W + PW[pos];  a1[n,h] = ft·al[h], a2[n,h] = ft·ar[h]
// 128x64 tile (BN=64 == DHEAD, so each x-block owns exactly one head),
// BK=16, 256 threads, 8x4 micro-tile.
__global__ __launch_bounds__(256) void gemm_attn_k(
    const float* __restrict__ A, const float* __restrict__ W,
    const float* __restrict__ PW, const int* __restrict__ pos,
    const float* __restrict__ al, const float* __restrict__ arw,
    float* __restrict__ C, float* __restrict__ a1, float* __restrict__ a2,
    int K){
  __shared__ float As[16][132];   // [k][m], +4 pad
  __shared__ float Bs[16][64];    // [k][n]
  int t  = threadIdx.x;
  int tx = t & 15, ty = t >> 4;
  int rowBase = blockIdx.y * 128;
  int colBase = blockIdx.x * 64;
  int h = blockIdx.x;             // head index (gridDim.x == 4)
  float acc[8][4] = {{0.f}};
  int ar = t >> 1;                // staging row 0..127
  int ac = (t & 1) * 8;           // k offset 0 / 8
  int bk = t >> 4;                // B stage k row
  int bj = (t & 15) * 4;          // B stage col group

  for (int kb = 0; kb < K; kb += 16){
    int arow = rowBase + ar;
    float4 v0 = make_float4(0.f,0.f,0.f,0.f), v1 = v0;
    if (arow < N_NODES){
      const float* ap = &A[(size_t)arow * K + kb + ac];
      v0 = *(const float4*)ap;
      v1 = *(const float4*)(ap + 4);
    }
    As[ac+0][ar]=v0.x; As[ac+1][ar]=v0.y; As[ac+2][ar]=v0.z; As[ac+3][ar]=v0.w;
    As[ac+4][ar]=v1.x; As[ac+5][ar]=v1.y; As[ac+6][ar]=v1.z; As[ac+7][ar]=v1.w;
    *(float4*)&Bs[bk][bj] =
        *(const float4*)&W[(size_t)(kb + bk) * FDIM + colBase + bj];
    __syncthreads();
#pragma unroll
    for (int kk = 0; kk < 16; kk++){
      float4 b  = *(const float4*)&Bs[kk][tx * 4];
      float4 a0 = *(const float4*)&As[kk][ty * 8];
      float4 a1v= *(const float4*)&As[kk][ty * 8 + 4];
      float aa[8] = {a0.x,a0.y,a0.z,a0.w,a1v.x,a1v.y,a1v.z,a1v.w};
      float bb[4] = {b.x,b.y,b.z,b.w};
#pragma unroll
      for (int i = 0; i < 8; i++)
#pragma unroll
        for (int j = 0; j < 4; j++)
          acc[i][j] = fmaf(aa[i], bb[j], acc[i][j]);
    }
    __syncthreads();
  }

  float4 alv = *(const float4*)&al[h * DHEAD + tx * 4];
  float4 arv = *(const float4*)&arw[h * DHEAD + tx * 4];
#pragma unroll
  for (int i = 0; i < 8; i++){
    int row = rowBase + ty * 8 + i;
    if (row >= N_NODES) continue;
    int p = pos[row];
    float4 pw = *(const float4*)&PW[p * FDIM + colBase + tx * 4];
    float4 o;
    o.x = acc[i][0] + pw.x; o.y = acc[i][1] + pw.y;
    o.z = acc[i][2] + pw.z; o.w = acc[i][3] + pw.w;
    *(float4*)&C[(size_t)row * FDIM + colBase + tx * 4] = o;
    // fused a1/a2: dot over this head's 64 cols (16 lanes x 4)
    float s1 = o.x*alv.x + o.y*alv.y + o.z*alv.z + o.w*alv.w;
    float s2 = o.x*arv.x + o.y*arv.y + o.z*arv.z + o.w*arv.w;
#pragma unroll
    for (int o2 = 8; o2 > 0; o2 >>= 1){
      s1 += __shfl_xor(s1, o2, 64);
      s2 += __shfl_xor(s2, o2, 64);
    }
    if (tx == 0){
      a1[row * HEADS + h] = s1;
      a2[row * HEADS + h] = s2;
    }
  }
}

// ---------------- per-dst softmax + aggregate (+ ELU or head-mean) ----------------
// one block per node; phase A: wave = head; phase B: 4 edge slots x float4 dims
__global__ __launch_bounds__(256) void agg2_k(
    const float* __restrict__ ft, const float* __restrict__ a1,
    const float* __restrict__ a2, const int* __restrict__ off,
    const int* __restrict__ esrc, float* __restrict__ out, int mode){
  __shared__ float m_s[HEADS], inv_s[HEADS];
  __shared__ float red[4][FDIM];
  __shared__ float tot[FDIM];
  int n = blockIdx.x;
  int t = threadIdx.x;
  int jb = off[n], je = off[n + 1];

  // phase A: per-head max and 1/sum(exp); e_j = lrelu(a1[src]+a2[n])
  {
    int h = t >> 6, l = t & 63;
    float a2n = a2[n * HEADS + h];
    float m = -INFINITY;
    for (int j = jb + l; j < je; j += 64){
      int s = esrc[j];
      m = fmaxf(m, lrelu(a1[s * HEADS + h] + a2n));
    }
    m = wave_red_max(m);
    float ss = 0.f;
    for (int j = jb + l; j < je; j += 64){
      int s = esrc[j];
      ss += __expf(lrelu(a1[s * HEADS + h] + a2n) - m);
    }
    ss = wave_red_sum(ss);
    if (l == 0){
      m_s[h] = m;
      inv_s[h] = (ss > 0.f) ? 1.f / ss : 0.f;
    }
  }
  __syncthreads();

  // phase B: 4 edges in flight, float4 feature loads
  int slot = t >> 6, li = t & 63, hh = li >> 4;
  float mm = m_s[hh], iv = inv_s[hh];
  float a2n = a2[n * HEADS + hh];
  float4 acc = make_float4(0.f, 0.f, 0.f, 0.f);
  for (int j = jb + slot; j < je; j += 4){
    int s = esrc[j];
    float e = lrelu(a1[s * HEADS + hh] + a2n);
    float w = __expf(e - mm) * iv;
    float4 f = *(const float4*)&ft[(size_t)s * FDIM + li * 4];
    acc.x = fmaf(w, f.x, acc.x);
    acc.y = fmaf(w, f.y, acc.y);
    acc.z = fmaf(w, f.z, acc.z);
    acc.w = fmaf(w, f.w, acc.w);
  }
  *(float4*)&red[slot][li * 4] = acc;
  __syncthreads();

  if (slot == 0){
    float4 r0 = *(float4*)&red[0][li * 4];
    float4 r1 = *(float4*)&red[1][li * 4];
    float4 r2 = *(float4*)&red[2][li * 4];
    float4 r3 = *(float4*)&red[3][li * 4];
    float4 s4;
    s4.x = r0.x + r1.x + r2.x + r3.x;
    s4.y = r0.y + r1.y + r2.y + r3.y;
    s4.z = r0.z + r1.z + r2.z + r3.z;
    s4.w = r0.w + r1.w + r2.w + r3.w;
    if (mode == 0){
      s4.x = s4.x > 0.f ? s4.x : (__expf(s4.x) - 1.f);
      s4.y = s4.y > 0.f ? s4.y : (__expf(s4.y) - 1.f);
      s4.z = s4.z > 0.f ? s4.z : (__expf(s4.z) - 1.f);
      s4.w = s4.w > 0.f ? s4.w : (__expf(s4.w) - 1.f);
      *(float4*)&out[(size_t)n * FDIM + li * 4] = s4;
    } else {
      *(float4*)&tot[li * 4] = s4;
    }
  }
  if (mode == 1){
    __syncthreads();
    if (t < DHEAD)
      out[(size_t)n * DHEAD + t] =
          0.25f * (tot[t] + tot[t + 64] + tot[t + 128] + tot[t + 192]);
  }
}

// ---------------- launch ----------------
extern "C" void kernel_launch(void* const* d_in, const int* in_sizes, int n_in,
                              void* d_out, int out_size, void* d_ws, size_t ws_size,
                              hipStream_t stream){
  const float* features = (const float*)d_in[0];
  const float* W0  = (const float*)d_in[1];
  const float* al0 = (const float*)d_in[2];
  const float* ar0 = (const float*)d_in[3];
  const float* pe0 = (const float*)d_in[4];
  const float* W1  = (const float*)d_in[5];
  const float* al1 = (const float*)d_in[6];
  const float* ar1 = (const float*)d_in[7];
  const float* pe1 = (const float*)d_in[8];
  const float* W2  = (const float*)d_in[9];
  const float* al2 = (const float*)d_in[10];
  const float* ar2 = (const float*)d_in[11];
  const float* pe2 = (const float*)d_in[12];
  const int* srcv  = (const int*)d_in[13];
  const int* dstv  = (const int*)d_in[14];
  const int* posv  = (const int*)d_in[15];
  float* out = (float*)d_out;

  char* wp = (char*)d_ws;
  auto alloc = [&](size_t bytes){
    void* p = (void*)wp;
    wp += (bytes + 255) & ~(size_t)255;
    return p;
  };
  float* ft     = (float*)alloc(sizeof(float) * (size_t)N_NODES * FDIM);
  float* hbuf   = (float*)alloc(sizeof(float) * (size_t)N_NODES * FDIM);
  float* a1     = (float*)alloc(sizeof(float) * N_NODES * HEADS);
  float* a2     = (float*)alloc(sizeof(float) * N_NODES * HEADS);
  float* PW     = (float*)alloc(sizeof(float) * 3 * FDIM);
  int*   deg    = (int*)alloc(sizeof(int) * N_NODES);
  int*   off    = (int*)alloc(sizeof(int) * (N_NODES + 1));
  int*   cursor = (int*)alloc(sizeof(int) * N_NODES);
  int*   bsum   = (int*)alloc(sizeof(int) * 64);
  int*   boff   = (int*)alloc(sizeof(int) * 64);
  int*   esrc   = (int*)alloc(sizeof(int) * N_EDGES);

  // CSR build (graph identical for all 3 layers)
  hipMemsetAsync(deg, 0, sizeof(int) * N_NODES, stream);
  hist_k<<<(N_EDGES + 255) / 256, 256, 0, stream>>>(dstv, deg);
  scanA_k<<<SCAN_NB, SCAN_B, 0, stream>>>(deg, off, bsum);
  scanB_k<<<1, 64, 0, stream>>>(bsum, boff);
  scanC_k<<<SCAN_NB, SCAN_B, 0, stream>>>(off, boff, cursor);
  scatter_k<<<(N_EDGES + 255) / 256, 256, 0, stream>>>(srcv, dstv, cursor, esrc);

  dim3 ggrid(4, (N_NODES + 127) / 128);

  // layer 0 (K=128)
  pw_k<<<3, 256, 0, stream>>>(W0, pe0, PW, 128);
  gemm_attn_k<<<ggrid, 256, 0, stream>>>(features, W0, PW, posv, al0, ar0,
                                         ft, a1, a2, 128);
  agg2_k<<<N_NODES, 256, 0, stream>>>(ft, a1, a2, off, esrc, hbuf, 0);

  // layer 1 (K=256)
  pw_k<<<3, 256, 0, stream>>>(W1, pe1, PW, 256);
  gemm_attn_k<<<ggrid, 256, 0, stream>>>(hbuf, W1, PW, posv, al1, ar1,
                                         ft, a1, a2, 256);
  agg2_k<<<N_NODES, 256, 0, stream>>>(ft, a1, a2, off, esrc, hbuf, 0);

  // layer 2 (K=256, head-mean -> d_out)
  pw_k<<<3, 256, 0, stream>>>(W2, pe2, PW, 256);
  gemm_attn_k<<<ggrid, 256, 0, stream>>>(hbuf, W2, PW, posv, al2, ar2,
                                         ft, a1, a2, 256);
  agg2_k<<<N_NODES, 256, 0, stream>>>(ft, a1, a2, off, esrc, out, 1);
}

// Round 4
// 514.043 us; speedup vs baseline: 1.5112x; 1.1218x over previous
//
#include <hip/hip_runtime.h>
#include <hip/hip_fp16.h>
#include <math.h>

#define N_NODES 30000
#define N_EDGES 480000
#define HEADS 4
#define DHEAD 64
#define FDIM 256   // HEADS * DHEAD
#define POSD 32
#define SCAN_B 1024
#define SCAN_NB ((N_NODES + SCAN_B - 1) / SCAN_B)   // 30
#define CAP 96     // LDS-cached edges per node (Poisson(16): P(deg>96) ~ 0)

__device__ __forceinline__ float wave_red_sum(float v){
#pragma unroll
  for (int o = 32; o > 0; o >>= 1) v += __shfl_xor(v, o, 64);
  return v;
}
__device__ __forceinline__ float wave_red_max(float v){
#pragma unroll
  for (int o = 32; o > 0; o >>= 1) v = fmaxf(v, __shfl_xor(v, o, 64));
  return v;
}
__device__ __forceinline__ float lrelu(float x){ return x > 0.f ? x : 0.2f * x; }

// ---------------- CSR build ----------------
__global__ void hist_k(const int* __restrict__ dst, int* __restrict__ deg){
  int e = blockIdx.x * blockDim.x + threadIdx.x;
  if (e < N_EDGES) atomicAdd(&deg[dst[e]], 1);
}

__global__ void scanA_k(const int* __restrict__ deg, int* __restrict__ off,
                        int* __restrict__ bsum){
  __shared__ int sm[SCAN_B];
  int t = threadIdx.x;
  int i = blockIdx.x * SCAN_B + t;
  int x = (i < N_NODES) ? deg[i] : 0;
  sm[t] = x;
  __syncthreads();
#pragma unroll
  for (int o = 1; o < SCAN_B; o <<= 1){
    int v = (t >= o) ? sm[t - o] : 0;
    __syncthreads();
    sm[t] += v;
    __syncthreads();
  }
  if (i < N_NODES) off[i] = sm[t] - x;
  if (t == SCAN_B - 1) bsum[blockIdx.x] = sm[t];
}

__global__ void scanB_k(int* __restrict__ bsum, int* __restrict__ boff){
  __shared__ int sm[64];
  int t = threadIdx.x;
  int x = (t < SCAN_NB) ? bsum[t] : 0;
  sm[t] = x;
  __syncthreads();
#pragma unroll
  for (int o = 1; o < 64; o <<= 1){
    int v = (t >= o) ? sm[t - o] : 0;
    __syncthreads();
    sm[t] += v;
    __syncthreads();
  }
  if (t < SCAN_NB) boff[t] = sm[t] - x;
}

__global__ void scanC_k(int* __restrict__ off, const int* __restrict__ boff,
                        int* __restrict__ cursor){
  int i = blockIdx.x * SCAN_B + threadIdx.x;
  if (i < N_NODES){
    int v = off[i] + boff[blockIdx.x];
    off[i] = v;
    cursor[i] = v;
  }
  if (i == 0) off[N_NODES] = N_EDGES;
}

__global__ void scatter_k(const int* __restrict__ src, const int* __restrict__ dst,
                          int* __restrict__ cursor, int* __restrict__ esrc){
  int e = blockIdx.x * blockDim.x + threadIdx.x;
  if (e < N_EDGES){
    int d = dst[e];
    int p = atomicAdd(&cursor[d], 1);
    esrc[p] = src[e];
  }
}

// ---------------- all 3 layers' pe[v] @ W_tail bias tables ----------------
__global__ void pw_k(const float* __restrict__ W0, const float* __restrict__ W1,
                     const float* __restrict__ W2, const float* __restrict__ pe0,
                     const float* __restrict__ pe1, const float* __restrict__ pe2,
                     float* __restrict__ PW){
  int layer = blockIdx.x / 3, v = blockIdx.x % 3;
  const float* W  = layer == 0 ? W0 : (layer == 1 ? W1 : W2);
  const float* pe = layer == 0 ? pe0 : (layer == 1 ? pe1 : pe2);
  int K = layer == 0 ? 128 : 256;
  int j = threadIdx.x;
  float s = 0.f;
#pragma unroll
  for (int k = 0; k < POSD; k++)
    s = fmaf(pe[v * POSD + k], W[(size_t)(K + k) * FDIM + j], s);
  PW[(layer * 3 + v) * FDIM + j] = s;
}

// ---------------- GEMM + fused attention coefficients, fp16 ft output ------
// 64x64 tile, 64 threads (1 wave), 8x8 micro-tile. BN=64 == DHEAD so each
// x-block is exactly one head. a1/a2 computed from fp32 acc; ft stored fp16.
__global__ __launch_bounds__(64, 4) void gemm_attn_k(
    const float* __restrict__ A, const float* __restrict__ W,
    const float* __restrict__ PW, const int* __restrict__ pos,
    const float* __restrict__ al, const float* __restrict__ arw,
    __half* __restrict__ Ch, float* __restrict__ a1, float* __restrict__ a2,
    int K){
  __shared__ float As[16][68];   // [k][m] +4 pad
  __shared__ float Bs[16][68];   // [k][n] +4 pad
  int t  = threadIdx.x;
  int tx = t & 7, ty = t >> 3;
  int rowBase = blockIdx.y * 64;
  int h = blockIdx.x;            // head
  int colBase = h * 64;
  float acc[8][8] = {{0.f}};
  int bk = t >> 2, bc = (t & 3) * 16;   // B staging: row bk, 16 cols at bc

  for (int kb = 0; kb < K; kb += 16){
    int arow = rowBase + t;
    float4 v0 = make_float4(0.f,0.f,0.f,0.f), v1 = v0, v2 = v0, v3 = v0;
    if (arow < N_NODES){
      const float* ap = &A[(size_t)arow * K + kb];
      v0 = *(const float4*)ap;
      v1 = *(const float4*)(ap + 4);
      v2 = *(const float4*)(ap + 8);
      v3 = *(const float4*)(ap + 12);
    }
    As[ 0][t]=v0.x; As[ 1][t]=v0.y; As[ 2][t]=v0.z; As[ 3][t]=v0.w;
    As[ 4][t]=v1.x; As[ 5][t]=v1.y; As[ 6][t]=v1.z; As[ 7][t]=v1.w;
    As[ 8][t]=v2.x; As[ 9][t]=v2.y; As[10][t]=v2.z; As[11][t]=v2.w;
    As[12][t]=v3.x; As[13][t]=v3.y; As[14][t]=v3.z; As[15][t]=v3.w;
    {
      const float* wp = &W[(size_t)(kb + bk) * FDIM + colBase + bc];
      *(float4*)&Bs[bk][bc +  0] = *(const float4*)(wp + 0);
      *(float4*)&Bs[bk][bc +  4] = *(const float4*)(wp + 4);
      *(float4*)&Bs[bk][bc +  8] = *(const float4*)(wp + 8);
      *(float4*)&Bs[bk][bc + 12] = *(const float4*)(wp + 12);
    }
    __syncthreads();
#pragma unroll
    for (int kk = 0; kk < 16; kk++){
      float4 a0 = *(const float4*)&As[kk][ty * 8];
      float4 a1v= *(const float4*)&As[kk][ty * 8 + 4];
      float4 b0 = *(const float4*)&Bs[kk][tx * 8];
      float4 b1 = *(const float4*)&Bs[kk][tx * 8 + 4];
      float aa[8] = {a0.x,a0.y,a0.z,a0.w,a1v.x,a1v.y,a1v.z,a1v.w};
      float bb[8] = {b0.x,b0.y,b0.z,b0.w,b1.x,b1.y,b1.z,b1.w};
#pragma unroll
      for (int i = 0; i < 8; i++)
#pragma unroll
        for (int j = 0; j < 8; j++)
          acc[i][j] = fmaf(aa[i], bb[j], acc[i][j]);
    }
    __syncthreads();
  }

  float4 al0 = *(const float4*)&al [h * DHEAD + tx * 8];
  float4 al1 = *(const float4*)&al [h * DHEAD + tx * 8 + 4];
  float4 ar0 = *(const float4*)&arw[h * DHEAD + tx * 8];
  float4 ar1 = *(const float4*)&arw[h * DHEAD + tx * 8 + 4];
  float alw[8] = {al0.x,al0.y,al0.z,al0.w,al1.x,al1.y,al1.z,al1.w};
  float arr[8] = {ar0.x,ar0.y,ar0.z,ar0.w,ar1.x,ar1.y,ar1.z,ar1.w};

#pragma unroll
  for (int i = 0; i < 8; i++){
    int row = rowBase + ty * 8 + i;
    if (row >= N_NODES) continue;
    int p = pos[row];
    const float* pw = &PW[p * FDIM + colBase + tx * 8];
    float o[8];
#pragma unroll
    for (int j = 0; j < 8; j++) o[j] = acc[i][j] + pw[j];
    union { __half hv[8]; int4 v4; } u;
#pragma unroll
    for (int j = 0; j < 8; j++) u.hv[j] = __float2half(o[j]);
    *(int4*)&Ch[(size_t)row * FDIM + colBase + tx * 8] = u.v4;
    float s1 = 0.f, s2 = 0.f;
#pragma unroll
    for (int j = 0; j < 8; j++){
      s1 = fmaf(o[j], alw[j], s1);
      s2 = fmaf(o[j], arr[j], s2);
    }
#pragma unroll
    for (int o2 = 4; o2 > 0; o2 >>= 1){
      s1 += __shfl_xor(s1, o2, 64);
      s2 += __shfl_xor(s2, o2, 64);
    }
    if (tx == 0){
      a1[row * HEADS + h] = s1;
      a2[row * HEADS + h] = s2;
    }
  }
}

// ---------------- per-dst softmax + aggregate (fp16 gather) ----------------
// one block per node; phase A: wave=head computes normalized weights into LDS;
// phase B: 4 edge slots, fp16 row gather, unroll-by-2.
__global__ __launch_bounds__(256) void agg3_k(
    const __half* __restrict__ ft, const float* __restrict__ a1,
    const float* __restrict__ a2, const int* __restrict__ off,
    const int* __restrict__ esrc, float* __restrict__ out, int mode){
  __shared__ float w_s[CAP][HEADS];
  __shared__ float m_s[HEADS], inv_s[HEADS];
  __shared__ float red[4][FDIM];
  int n = blockIdx.x;
  int t = threadIdx.x;
  int jb = off[n], je = off[n + 1];
  int deg = je - jb;

  // phase A: wave h owns head h
  {
    int h = t >> 6, l = t & 63;
    float a2n = a2[n * HEADS + h];
    float m = -INFINITY;
    for (int idx = l; idx < deg; idx += 64){
      int s = esrc[jb + idx];
      float e = lrelu(a1[s * HEADS + h] + a2n);
      if (idx < CAP) w_s[idx][h] = e;
      m = fmaxf(m, e);
    }
    m = wave_red_max(m);
    float ss = 0.f;
    for (int idx = l; idx < deg; idx += 64){
      float e;
      if (idx < CAP) e = w_s[idx][h];
      else { int s = esrc[jb + idx]; e = lrelu(a1[s * HEADS + h] + a2n); }
      ss += __expf(e - m);
    }
    ss = wave_red_sum(ss);
    float inv = (ss > 0.f) ? 1.f / ss : 0.f;
    for (int idx = l; idx < deg && idx < CAP; idx += 64)
      w_s[idx][h] = __expf(w_s[idx][h] - m) * inv;
    if (l == 0){ m_s[h] = m; inv_s[h] = inv; }
  }
  __syncthreads();

  // phase B
  int slot = t >> 6, li = t & 63, hh = li >> 4;
  float mm = m_s[hh], iv = inv_s[hh];
  float a2n = a2[n * HEADS + hh];
  struct h4 { __half2 a, b; };
  float4 acc0 = make_float4(0.f,0.f,0.f,0.f), acc1 = acc0;
  int idx = slot;
  for (; idx + 4 < deg; idx += 8){
    int s0 = esrc[jb + idx], s1 = esrc[jb + idx + 4];
    float w0 = (idx < CAP) ? w_s[idx][hh]
             : __expf(lrelu(a1[s0 * HEADS + hh] + a2n) - mm) * iv;
    float w1 = (idx + 4 < CAP) ? w_s[idx + 4][hh]
             : __expf(lrelu(a1[s1 * HEADS + hh] + a2n) - mm) * iv;
    h4 f0 = *(const h4*)&ft[(size_t)s0 * FDIM + li * 4];
    h4 f1 = *(const h4*)&ft[(size_t)s1 * FDIM + li * 4];
    float2 f0a = __half22float2(f0.a), f0b = __half22float2(f0.b);
    float2 f1a = __half22float2(f1.a), f1b = __half22float2(f1.b);
    acc0.x = fmaf(w0, f0a.x, acc0.x); acc0.y = fmaf(w0, f0a.y, acc0.y);
    acc0.z = fmaf(w0, f0b.x, acc0.z); acc0.w = fmaf(w0, f0b.y, acc0.w);
    acc1.x = fmaf(w1, f1a.x, acc1.x); acc1.y = fmaf(w1, f1a.y, acc1.y);
    acc1.z = fmaf(w1, f1b.x, acc1.z); acc1.w = fmaf(w1, f1b.y, acc1.w);
  }
  for (; idx < deg; idx += 4){
    int s0 = esrc[jb + idx];
    float w0 = (idx < CAP) ? w_s[idx][hh]
             : __expf(lrelu(a1[s0 * HEADS + hh] + a2n) - mm) * iv;
    h4 f0 = *(const h4*)&ft[(size_t)s0 * FDIM + li * 4];
    float2 f0a = __half22float2(f0.a), f0b = __half22float2(f0.b);
    acc0.x = fmaf(w0, f0a.x, acc0.x); acc0.y = fmaf(w0, f0a.y, acc0.y);
    acc0.z = fmaf(w0, f0b.x, acc0.z); acc0.w = fmaf(w0, f0b.y, acc0.w);
  }
  acc0.x += acc1.x; acc0.y += acc1.y; acc0.z += acc1.z; acc0.w += acc1.w;

  if (slot != 0) *(float4*)&red[slot][li * 4] = acc0;
  __syncthreads();
  if (slot == 0){
    float4 r1 = *(float4*)&red[1][li * 4];
    float4 r2 = *(float4*)&red[2][li * 4];
    float4 r3 = *(float4*)&red[3][li * 4];
    float4 s4;
    s4.x = acc0.x + r1.x + r2.x + r3.x;
    s4.y = acc0.y + r1.y + r2.y + r3.y;
    s4.z = acc0.z + r1.z + r2.z + r3.z;
    s4.w = acc0.w + r1.w + r2.w + r3.w;
    if (mode == 0){
      s4.x = s4.x > 0.f ? s4.x : (__expf(s4.x) - 1.f);
      s4.y = s4.y > 0.f ? s4.y : (__expf(s4.y) - 1.f);
      s4.z = s4.z > 0.f ? s4.z : (__expf(s4.z) - 1.f);
      s4.w = s4.w > 0.f ? s4.w : (__expf(s4.w) - 1.f);
      *(float4*)&out[(size_t)n * FDIM + li * 4] = s4;
    } else {
      *(float4*)&red[0][li * 4] = s4;
    }
  }
  if (mode == 1){
    __syncthreads();
    if (t < DHEAD)
      out[(size_t)n * DHEAD + t] =
          0.25f * (red[0][t] + red[0][t + 64] + red[0][t + 128] + red[0][t + 192]);
  }
}

// ---------------- launch ----------------
extern "C" void kernel_launch(void* const* d_in, const int* in_sizes, int n_in,
                              void* d_out, int out_size, void* d_ws, size_t ws_size,
                              hipStream_t stream){
  const float* features = (const float*)d_in[0];
  const float* W0  = (const float*)d_in[1];
  const float* al0 = (const float*)d_in[2];
  const float* ar0 = (const float*)d_in[3];
  const float* pe0 = (const float*)d_in[4];
  const float* W1  = (const float*)d_in[5];
  const float* al1 = (const float*)d_in[6];
  const float* ar1 = (const float*)d_in[7];
  const float* pe1 = (const float*)d_in[8];
  const float* W2  = (const float*)d_in[9];
  const float* al2 = (const float*)d_in[10];
  const float* ar2 = (const float*)d_in[11];
  const float* pe2 = (const float*)d_in[12];
  const int* srcv  = (const int*)d_in[13];
  const int* dstv  = (const int*)d_in[14];
  const int* posv  = (const int*)d_in[15];
  float* out = (float*)d_out;

  char* wp = (char*)d_ws;
  auto alloc = [&](size_t bytes){
    void* p = (void*)wp;
    wp += (bytes + 255) & ~(size_t)255;
    return p;
  };
  __half* fth   = (__half*)alloc(sizeof(__half) * (size_t)N_NODES * FDIM);
  float* hbuf   = (float*)alloc(sizeof(float) * (size_t)N_NODES * FDIM);
  float* a1     = (float*)alloc(sizeof(float) * N_NODES * HEADS);
  float* a2     = (float*)alloc(sizeof(float) * N_NODES * HEADS);
  float* PW     = (float*)alloc(sizeof(float) * 9 * FDIM);
  int*   deg    = (int*)alloc(sizeof(int) * N_NODES);
  int*   off    = (int*)alloc(sizeof(int) * (N_NODES + 1));
  int*   cursor = (int*)alloc(sizeof(int) * N_NODES);
  int*   bsum   = (int*)alloc(sizeof(int) * 64);
  int*   boff   = (int*)alloc(sizeof(int) * 64);
  int*   esrc   = (int*)alloc(sizeof(int) * N_EDGES);

  // CSR build (graph identical for all 3 layers)
  hipMemsetAsync(deg, 0, sizeof(int) * N_NODES, stream);
  hist_k<<<(N_EDGES + 255) / 256, 256, 0, stream>>>(dstv, deg);
  scanA_k<<<SCAN_NB, SCAN_B, 0, stream>>>(deg, off, bsum);
  scanB_k<<<1, 64, 0, stream>>>(bsum, boff);
  scanC_k<<<SCAN_NB, SCAN_B, 0, stream>>>(off, boff, cursor);
  scatter_k<<<(N_EDGES + 255) / 256, 256, 0, stream>>>(srcv, dstv, cursor, esrc);

  pw_k<<<9, 256, 0, stream>>>(W0, W1, W2, pe0, pe1, pe2, PW);

  dim3 ggrid(HEADS, (N_NODES + 63) / 64);

  // layer 0 (K=128)
  gemm_attn_k<<<ggrid, 64, 0, stream>>>(features, W0, PW + 0 * 3 * FDIM, posv,
                                        al0, ar0, fth, a1, a2, 128);
  agg3_k<<<N_NODES, 256, 0, stream>>>(fth, a1, a2, off, esrc, hbuf, 0);

  // layer 1 (K=256)
  gemm_attn_k<<<ggrid, 64, 0, stream>>>(hbuf, W1, PW + 1 * 3 * FDIM, posv,
                                        al1, ar1, fth, a1, a2, 256);
  agg3_k<<<N_NODES, 256, 0, stream>>>(fth, a1, a2, off, esrc, hbuf, 0);

  // layer 2 (K=256, head-mean -> d_out)
  gemm_attn_k<<<ggrid, 64, 0, stream>>>(hbuf, W2, PW + 2 * 3 * FDIM, posv,
                                        al2, ar2, fth, a1, a2, 256);
  agg3_k<<<N_NODES, 256, 0, stream>>>(fth, a1, a2, off, esrc, out, 1);
}

// Round 5
// 423.466 us; speedup vs baseline: 1.8345x; 1.2139x over previous
//
#include <hip/hip_runtime.h>
#include <hip/hip_fp16.h>
#include <math.h>

#define N_NODES 30000
#define N_EDGES 480000
#define HEADS 4
#define DHEAD 64
#define FDIM 256   // HEADS * DHEAD
#define POSD 32
#define SCAN_B 1024
#define SCAN_NB ((N_NODES + SCAN_B - 1) / SCAN_B)   // 30
#define CAP 96     // LDS-cached edges per node

typedef _Float16 half8 __attribute__((ext_vector_type(8)));
typedef float floatx4 __attribute__((ext_vector_type(4)));

__device__ __forceinline__ float wave_red_sum(float v){
#pragma unroll
  for (int o = 32; o > 0; o >>= 1) v += __shfl_xor(v, o, 64);
  return v;
}
__device__ __forceinline__ float wave_red_max(float v){
#pragma unroll
  for (int o = 32; o > 0; o >>= 1) v = fmaxf(v, __shfl_xor(v, o, 64));
  return v;
}
__device__ __forceinline__ float lrelu(float x){ return x > 0.f ? x : 0.2f * x; }

// ---------------- CSR build ----------------
__global__ void hist_k(const int* __restrict__ dst, int* __restrict__ deg){
  int e = blockIdx.x * blockDim.x + threadIdx.x;
  if (e < N_EDGES) atomicAdd(&deg[dst[e]], 1);
}

__global__ void scanA_k(const int* __restrict__ deg, int* __restrict__ off,
                        int* __restrict__ bsum){
  __shared__ int sm[SCAN_B];
  int t = threadIdx.x;
  int i = blockIdx.x * SCAN_B + t;
  int x = (i < N_NODES) ? deg[i] : 0;
  sm[t] = x;
  __syncthreads();
#pragma unroll
  for (int o = 1; o < SCAN_B; o <<= 1){
    int v = (t >= o) ? sm[t - o] : 0;
    __syncthreads();
    sm[t] += v;
    __syncthreads();
  }
  if (i < N_NODES) off[i] = sm[t] - x;
  if (t == SCAN_B - 1) bsum[blockIdx.x] = sm[t];
}

__global__ void scanB_k(int* __restrict__ bsum, int* __restrict__ boff){
  __shared__ int sm[64];
  int t = threadIdx.x;
  int x = (t < SCAN_NB) ? bsum[t] : 0;
  sm[t] = x;
  __syncthreads();
#pragma unroll
  for (int o = 1; o < 64; o <<= 1){
    int v = (t >= o) ? sm[t - o] : 0;
    __syncthreads();
    sm[t] += v;
    __syncthreads();
  }
  if (t < SCAN_NB) boff[t] = sm[t] - x;
}

__global__ void scanC_k(int* __restrict__ off, const int* __restrict__ boff,
                        int* __restrict__ cursor){
  int i = blockIdx.x * SCAN_B + threadIdx.x;
  if (i < N_NODES){
    int v = off[i] + boff[blockIdx.x];
    off[i] = v;
    cursor[i] = v;
  }
  if (i == 0) off[N_NODES] = N_EDGES;
}

__global__ void scatter_k(const int* __restrict__ src, const int* __restrict__ dst,
                          int* __restrict__ cursor, int* __restrict__ esrc){
  int e = blockIdx.x * blockDim.x + threadIdx.x;
  if (e < N_EDGES){
    int d = dst[e];
    int p = atomicAdd(&cursor[d], 1);
    esrc[p] = src[e];
  }
}

// ---------------- all 3 layers' pe[v] @ W_tail bias tables (fp32) ----------
__global__ void pw_k(const float* __restrict__ W0, const float* __restrict__ W1,
                     const float* __restrict__ W2, const float* __restrict__ pe0,
                     const float* __restrict__ pe1, const float* __restrict__ pe2,
                     float* __restrict__ PW){
  int layer = blockIdx.x / 3, v = blockIdx.x % 3;
  const float* W  = layer == 0 ? W0 : (layer == 1 ? W1 : W2);
  const float* pe = layer == 0 ? pe0 : (layer == 1 ? pe1 : pe2);
  int K = layer == 0 ? 128 : 256;
  int j = threadIdx.x;
  float s = 0.f;
#pragma unroll
  for (int k = 0; k < POSD; k++)
    s = fmaf(pe[v * POSD + k], W[(size_t)(K + k) * FDIM + j], s);
  PW[(layer * 3 + v) * FDIM + j] = s;
}

// ---------------- features fp32 -> fp16 ----------------
__global__ void f2h_k(const float* __restrict__ in, _Float16* __restrict__ out,
                      int n){
  int i = (blockIdx.x * blockDim.x + threadIdx.x) * 4;
  if (i < n){
    float4 v = *(const float4*)&in[i];
    struct h4s { _Float16 h[4]; } u;
    u.h[0] = (_Float16)v.x; u.h[1] = (_Float16)v.y;
    u.h[2] = (_Float16)v.z; u.h[3] = (_Float16)v.w;
    *(h4s*)&out[i] = u;
  }
}

// ---------------- W fp32 [K][256] -> fp16 transposed Wt[n][K] --------------
__global__ void wcvt_k(const float* __restrict__ W0, const float* __restrict__ W1,
                       const float* __restrict__ W2, _Float16* __restrict__ T0,
                       _Float16* __restrict__ T1, _Float16* __restrict__ T2){
  int l = blockIdx.y;
  const float* W = l == 0 ? W0 : (l == 1 ? W1 : W2);
  _Float16* T    = l == 0 ? T0 : (l == 1 ? T1 : T2);
  int K = l == 0 ? 128 : 256;
  int n = threadIdx.x;   // 0..255
  for (int k = blockIdx.x; k < K; k += gridDim.x)
    T[(size_t)n * K + k] = (_Float16)W[(size_t)k * FDIM + n];
}

// ---------------- MFMA GEMM + fused bias + attention coefficients ----------
// C[N,256] = A[N,K] @ W + PW[pos]; ft stored fp16; a1/a2 from fp32 acc.
// Grid (4 heads, ceil(M/128)); 256 thr = 4 waves; wave = 32 rows x 64 cols;
// no LDS, no barriers: A/B fragments straight from global (B is L2-hot).
__global__ __launch_bounds__(256) void gemm_mfma_k(
    const _Float16* __restrict__ A, const _Float16* __restrict__ Wt,
    const float* __restrict__ PW, const int* __restrict__ pos,
    const float* __restrict__ al, const float* __restrict__ arw,
    _Float16* __restrict__ Ch, float* __restrict__ a1, float* __restrict__ a2,
    int K){
  int t = threadIdx.x;
  int w = t >> 6;
  int lane = t & 63;
  int lm = lane & 15;        // m (A) / n (B) / col (C)
  int kq = lane >> 4;        // quad: k-group for A/B, row-group for C
  int h = blockIdx.x;
  int rowBase = blockIdx.y * 128 + w * 32;
  int colBase = h * 64;

  floatx4 acc[2][4] = {};

  int r0 = min(rowBase + lm, N_NODES - 1);
  int r1 = min(rowBase + 16 + lm, N_NODES - 1);
  const _Float16* Ar0 = A + (size_t)r0 * K;
  const _Float16* Ar1 = A + (size_t)r1 * K;
  const _Float16* B0 = Wt + (size_t)(colBase + 0 * 16 + lm) * K;
  const _Float16* B1 = Wt + (size_t)(colBase + 1 * 16 + lm) * K;
  const _Float16* B2 = Wt + (size_t)(colBase + 2 * 16 + lm) * K;
  const _Float16* B3 = Wt + (size_t)(colBase + 3 * 16 + lm) * K;

  for (int kb = 0; kb < K; kb += 32){
    int ko = kb + kq * 8;
    half8 a0 = *(const half8*)(Ar0 + ko);
    half8 a1f = *(const half8*)(Ar1 + ko);
    half8 b0 = *(const half8*)(B0 + ko);
    half8 b1 = *(const half8*)(B1 + ko);
    half8 b2 = *(const half8*)(B2 + ko);
    half8 b3 = *(const half8*)(B3 + ko);
    acc[0][0] = __builtin_amdgcn_mfma_f32_16x16x32_f16(a0, b0, acc[0][0], 0, 0, 0);
    acc[0][1] = __builtin_amdgcn_mfma_f32_16x16x32_f16(a0, b1, acc[0][1], 0, 0, 0);
    acc[0][2] = __builtin_amdgcn_mfma_f32_16x16x32_f16(a0, b2, acc[0][2], 0, 0, 0);
    acc[0][3] = __builtin_amdgcn_mfma_f32_16x16x32_f16(a0, b3, acc[0][3], 0, 0, 0);
    acc[1][0] = __builtin_amdgcn_mfma_f32_16x16x32_f16(a1f, b0, acc[1][0], 0, 0, 0);
    acc[1][1] = __builtin_amdgcn_mfma_f32_16x16x32_f16(a1f, b1, acc[1][1], 0, 0, 0);
    acc[1][2] = __builtin_amdgcn_mfma_f32_16x16x32_f16(a1f, b2, acc[1][2], 0, 0, 0);
    acc[1][3] = __builtin_amdgcn_mfma_f32_16x16x32_f16(a1f, b3, acc[1][3], 0, 0, 0);
  }

  float alw[4], arr[4];
#pragma unroll
  for (int j = 0; j < 4; j++){
    alw[j] = al [h * DHEAD + j * 16 + lm];
    arr[j] = arw[h * DHEAD + j * 16 + lm];
  }

#pragma unroll
  for (int i = 0; i < 2; i++){
#pragma unroll
    for (int p = 0; p < 4; p++){
      int row = rowBase + i * 16 + kq * 4 + p;
      if (row >= N_NODES) continue;
      int pz = pos[row];
      const float* pwb = PW + pz * FDIM + colBase;
      float s1 = 0.f, s2 = 0.f;
#pragma unroll
      for (int j = 0; j < 4; j++){
        float v = acc[i][j][p] + pwb[j * 16 + lm];
        Ch[(size_t)row * FDIM + colBase + j * 16 + lm] = (_Float16)v;
        s1 = fmaf(v, alw[j], s1);
        s2 = fmaf(v, arr[j], s2);
      }
      s1 += __shfl_xor(s1, 1, 64); s2 += __shfl_xor(s2, 1, 64);
      s1 += __shfl_xor(s1, 2, 64); s2 += __shfl_xor(s2, 2, 64);
      s1 += __shfl_xor(s1, 4, 64); s2 += __shfl_xor(s2, 4, 64);
      s1 += __shfl_xor(s1, 8, 64); s2 += __shfl_xor(s2, 8, 64);
      if (lm == 0){
        a1[row * HEADS + h] = s1;
        a2[row * HEADS + h] = s2;
      }
    }
  }
}

// ---------------- per-dst softmax + aggregate (fp16 gather) ----------------
// mode 0: ELU -> fp16 hidden out; mode 1: head-mean -> fp32 d_out
__global__ __launch_bounds__(256) void agg3_k(
    const __half* __restrict__ ft, const float* __restrict__ a1,
    const float* __restrict__ a2, const int* __restrict__ off,
    const int* __restrict__ esrc, _Float16* __restrict__ outh,
    float* __restrict__ outf, int mode){
  __shared__ float w_s[CAP][HEADS];
  __shared__ float m_s[HEADS], inv_s[HEADS];
  __shared__ float red[4][FDIM];
  int n = blockIdx.x;
  int t = threadIdx.x;
  int jb = off[n], je = off[n + 1];
  int deg = je - jb;

  // phase A: wave h owns head h; normalized weights cached in LDS
  {
    int h = t >> 6, l = t & 63;
    float a2n = a2[n * HEADS + h];
    float m = -INFINITY;
    for (int idx = l; idx < deg; idx += 64){
      int s = esrc[jb + idx];
      float e = lrelu(a1[s * HEADS + h] + a2n);
      if (idx < CAP) w_s[idx][h] = e;
      m = fmaxf(m, e);
    }
    m = wave_red_max(m);
    float ss = 0.f;
    for (int idx = l; idx < deg; idx += 64){
      float e;
      if (idx < CAP) e = w_s[idx][h];
      else { int s = esrc[jb + idx]; e = lrelu(a1[s * HEADS + h] + a2n); }
      ss += __expf(e - m);
    }
    ss = wave_red_sum(ss);
    float inv = (ss > 0.f) ? 1.f / ss : 0.f;
    for (int idx = l; idx < deg && idx < CAP; idx += 64)
      w_s[idx][h] = __expf(w_s[idx][h] - m) * inv;
    if (l == 0){ m_s[h] = m; inv_s[h] = inv; }
  }
  __syncthreads();

  // phase B: 4 edge slots, fp16 row gather, unroll-by-2
  int slot = t >> 6, li = t & 63, hh = li >> 4;
  float mm = m_s[hh], iv = inv_s[hh];
  float a2n = a2[n * HEADS + hh];
  struct h4 { __half2 a, b; };
  float4 acc0 = make_float4(0.f,0.f,0.f,0.f), acc1 = acc0;
  int idx = slot;
  for (; idx + 4 < deg; idx += 8){
    int s0 = esrc[jb + idx], s1 = esrc[jb + idx + 4];
    float w0 = (idx < CAP) ? w_s[idx][hh]
             : __expf(lrelu(a1[s0 * HEADS + hh] + a2n) - mm) * iv;
    float w1 = (idx + 4 < CAP) ? w_s[idx + 4][hh]
             : __expf(lrelu(a1[s1 * HEADS + hh] + a2n) - mm) * iv;
    h4 f0 = *(const h4*)&ft[(size_t)s0 * FDIM + li * 4];
    h4 f1 = *(const h4*)&ft[(size_t)s1 * FDIM + li * 4];
    float2 f0a = __half22float2(f0.a), f0b = __half22float2(f0.b);
    float2 f1a = __half22float2(f1.a), f1b = __half22float2(f1.b);
    acc0.x = fmaf(w0, f0a.x, acc0.x); acc0.y = fmaf(w0, f0a.y, acc0.y);
    acc0.z = fmaf(w0, f0b.x, acc0.z); acc0.w = fmaf(w0, f0b.y, acc0.w);
    acc1.x = fmaf(w1, f1a.x, acc1.x); acc1.y = fmaf(w1, f1a.y, acc1.y);
    acc1.z = fmaf(w1, f1b.x, acc1.z); acc1.w = fmaf(w1, f1b.y, acc1.w);
  }
  for (; idx < deg; idx += 4){
    int s0 = esrc[jb + idx];
    float w0 = (idx < CAP) ? w_s[idx][hh]
             : __expf(lrelu(a1[s0 * HEADS + hh] + a2n) - mm) * iv;
    h4 f0 = *(const h4*)&ft[(size_t)s0 * FDIM + li * 4];
    float2 f0a = __half22float2(f0.a), f0b = __half22float2(f0.b);
    acc0.x = fmaf(w0, f0a.x, acc0.x); acc0.y = fmaf(w0, f0a.y, acc0.y);
    acc0.z = fmaf(w0, f0b.x, acc0.z); acc0.w = fmaf(w0, f0b.y, acc0.w);
  }
  acc0.x += acc1.x; acc0.y += acc1.y; acc0.z += acc1.z; acc0.w += acc1.w;

  if (slot != 0) *(float4*)&red[slot][li * 4] = acc0;
  __syncthreads();
  if (slot == 0){
    float4 r1 = *(float4*)&red[1][li * 4];
    float4 r2 = *(float4*)&red[2][li * 4];
    float4 r3 = *(float4*)&red[3][li * 4];
    float4 s4;
    s4.x = acc0.x + r1.x + r2.x + r3.x;
    s4.y = acc0.y + r1.y + r2.y + r3.y;
    s4.z = acc0.z + r1.z + r2.z + r3.z;
    s4.w = acc0.w + r1.w + r2.w + r3.w;
    if (mode == 0){
      s4.x = s4.x > 0.f ? s4.x : (__expf(s4.x) - 1.f);
      s4.y = s4.y > 0.f ? s4.y : (__expf(s4.y) - 1.f);
      s4.z = s4.z > 0.f ? s4.z : (__expf(s4.z) - 1.f);
      s4.w = s4.w > 0.f ? s4.w : (__expf(s4.w) - 1.f);
      struct h4s { _Float16 h[4]; } u;
      u.h[0] = (_Float16)s4.x; u.h[1] = (_Float16)s4.y;
      u.h[2] = (_Float16)s4.z; u.h[3] = (_Float16)s4.w;
      *(h4s*)&outh[(size_t)n * FDIM + li * 4] = u;
    } else {
      *(float4*)&red[0][li * 4] = s4;
    }
  }
  if (mode == 1){
    __syncthreads();
    if (t < DHEAD)
      outf[(size_t)n * DHEAD + t] =
          0.25f * (red[0][t] + red[0][t + 64] + red[0][t + 128] + red[0][t + 192]);
  }
}

// ---------------- launch ----------------
extern "C" void kernel_launch(void* const* d_in, const int* in_sizes, int n_in,
                              void* d_out, int out_size, void* d_ws, size_t ws_size,
                              hipStream_t stream){
  const float* features = (const float*)d_in[0];
  const float* W0  = (const float*)d_in[1];
  const float* al0 = (const float*)d_in[2];
  const float* ar0 = (const float*)d_in[3];
  const float* pe0 = (const float*)d_in[4];
  const float* W1  = (const float*)d_in[5];
  const float* al1 = (const float*)d_in[6];
  const float* ar1 = (const float*)d_in[7];
  const float* pe1 = (const float*)d_in[8];
  const float* W2  = (const float*)d_in[9];
  const float* al2 = (const float*)d_in[10];
  const float* ar2 = (const float*)d_in[11];
  const float* pe2 = (const float*)d_in[12];
  const int* srcv  = (const int*)d_in[13];
  const int* dstv  = (const int*)d_in[14];
  const int* posv  = (const int*)d_in[15];
  float* out = (float*)d_out;

  char* wp = (char*)d_ws;
  auto alloc = [&](size_t bytes){
    void* p = (void*)wp;
    wp += (bytes + 255) & ~(size_t)255;
    return p;
  };
  _Float16* fth   = (_Float16*)alloc(sizeof(_Float16) * (size_t)N_NODES * FDIM);
  _Float16* hbuf  = (_Float16*)alloc(sizeof(_Float16) * (size_t)N_NODES * FDIM);
  _Float16* feat16= (_Float16*)alloc(sizeof(_Float16) * (size_t)N_NODES * 128);
  _Float16* Wt0   = (_Float16*)alloc(sizeof(_Float16) * 256 * 128);
  _Float16* Wt1   = (_Float16*)alloc(sizeof(_Float16) * 256 * 256);
  _Float16* Wt2   = (_Float16*)alloc(sizeof(_Float16) * 256 * 256);
  float* a1     = (float*)alloc(sizeof(float) * N_NODES * HEADS);
  float* a2     = (float*)alloc(sizeof(float) * N_NODES * HEADS);
  float* PW     = (float*)alloc(sizeof(float) * 9 * FDIM);
  int*   deg    = (int*)alloc(sizeof(int) * N_NODES);
  int*   off    = (int*)alloc(sizeof(int) * (N_NODES + 1));
  int*   cursor = (int*)alloc(sizeof(int) * N_NODES);
  int*   bsum   = (int*)alloc(sizeof(int) * 64);
  int*   boff   = (int*)alloc(sizeof(int) * 64);
  int*   esrc   = (int*)alloc(sizeof(int) * N_EDGES);

  // CSR build (graph identical for all 3 layers)
  hipMemsetAsync(deg, 0, sizeof(int) * N_NODES, stream);
  hist_k<<<(N_EDGES + 255) / 256, 256, 0, stream>>>(dstv, deg);
  scanA_k<<<SCAN_NB, SCAN_B, 0, stream>>>(deg, off, bsum);
  scanB_k<<<1, 64, 0, stream>>>(bsum, boff);
  scanC_k<<<SCAN_NB, SCAN_B, 0, stream>>>(off, boff, cursor);
  scatter_k<<<(N_EDGES + 255) / 256, 256, 0, stream>>>(srcv, dstv, cursor, esrc);

  pw_k<<<9, 256, 0, stream>>>(W0, W1, W2, pe0, pe1, pe2, PW);
  f2h_k<<<(N_NODES * 128 / 4 + 255) / 256, 256, 0, stream>>>(
      features, feat16, N_NODES * 128);
  wcvt_k<<<dim3(64, 3), 256, 0, stream>>>(W0, W1, W2, Wt0, Wt1, Wt2);

  dim3 ggrid(HEADS, (N_NODES + 127) / 128);

  // layer 0 (K=128)
  gemm_mfma_k<<<ggrid, 256, 0, stream>>>(feat16, Wt0, PW + 0 * 3 * FDIM, posv,
                                         al0, ar0, fth, a1, a2, 128);
  agg3_k<<<N_NODES, 256, 0, stream>>>((const __half*)fth, a1, a2, off, esrc,
                                      hbuf, nullptr, 0);

  // layer 1 (K=256)
  gemm_mfma_k<<<ggrid, 256, 0, stream>>>(hbuf, Wt1, PW + 1 * 3 * FDIM, posv,
                                         al1, ar1, fth, a1, a2, 256);
  agg3_k<<<N_NODES, 256, 0, stream>>>((const __half*)fth, a1, a2, off, esrc,
                                      hbuf, nullptr, 0);

  // layer 2 (K=256, head-mean -> d_out)
  gemm_mfma_k<<<ggrid, 256, 0, stream>>>(hbuf, Wt2, PW + 2 * 3 * FDIM, posv,
                                         al2, ar2, fth, a1, a2, 256);
  agg3_k<<<N_NODES, 256, 0, stream>>>((const __half*)fth, a1, a2, off, esrc,
                                      nullptr, out, 1);
}

// Round 6
// 333.963 us; speedup vs baseline: 2.3261x; 1.2680x over previous
//
#include <hip/hip_runtime.h>
#include <hip/hip_fp16.h>
#include <math.h>

#define N_NODES 30000
#define N_EDGES 480000
#define HEADS 4
#define DHEAD 64
#define FDIM 256   // HEADS * DHEAD
#define POSD 32
#define SCAN_B 1024
#define SCAN_NB ((N_NODES + SCAN_B - 1) / SCAN_B)   // 30

typedef _Float16 half8 __attribute__((ext_vector_type(8)));
typedef float floatx4 __attribute__((ext_vector_type(4)));

__device__ __forceinline__ float lrelu(float x){ return x > 0.f ? x : 0.2f * x; }

// ---------------- CSR build ----------------
__global__ void hist_k(const int* __restrict__ dst, int* __restrict__ deg){
  int e = blockIdx.x * blockDim.x + threadIdx.x;
  if (e < N_EDGES) atomicAdd(&deg[dst[e]], 1);
}

__global__ void scanA_k(const int* __restrict__ deg, int* __restrict__ off,
                        int* __restrict__ bsum){
  __shared__ int sm[SCAN_B];
  int t = threadIdx.x;
  int i = blockIdx.x * SCAN_B + t;
  int x = (i < N_NODES) ? deg[i] : 0;
  sm[t] = x;
  __syncthreads();
#pragma unroll
  for (int o = 1; o < SCAN_B; o <<= 1){
    int v = (t >= o) ? sm[t - o] : 0;
    __syncthreads();
    sm[t] += v;
    __syncthreads();
  }
  if (i < N_NODES) off[i] = sm[t] - x;
  if (t == SCAN_B - 1) bsum[blockIdx.x] = sm[t];
}

__global__ void scanB_k(int* __restrict__ bsum, int* __restrict__ boff){
  __shared__ int sm[64];
  int t = threadIdx.x;
  int x = (t < SCAN_NB) ? bsum[t] : 0;
  sm[t] = x;
  __syncthreads();
#pragma unroll
  for (int o = 1; o < 64; o <<= 1){
    int v = (t >= o) ? sm[t - o] : 0;
    __syncthreads();
    sm[t] += v;
    __syncthreads();
  }
  if (t < SCAN_NB) boff[t] = sm[t] - x;
}

__global__ void scanC_k(int* __restrict__ off, const int* __restrict__ boff,
                        int* __restrict__ cursor){
  int i = blockIdx.x * SCAN_B + threadIdx.x;
  if (i < N_NODES){
    int v = off[i] + boff[blockIdx.x];
    off[i] = v;
    cursor[i] = v;
  }
  if (i == 0) off[N_NODES] = N_EDGES;
}

__global__ void scatter_k(const int* __restrict__ src, const int* __restrict__ dst,
                          int* __restrict__ cursor, int* __restrict__ esrc){
  int e = blockIdx.x * blockDim.x + threadIdx.x;
  if (e < N_EDGES){
    int d = dst[e];
    int p = atomicAdd(&cursor[d], 1);
    esrc[p] = src[e];
  }
}

// ---------------- all 3 layers' pe[v] @ W_tail bias tables (fp32) ----------
__global__ void pw_k(const float* __restrict__ W0, const float* __restrict__ W1,
                     const float* __restrict__ W2, const float* __restrict__ pe0,
                     const float* __restrict__ pe1, const float* __restrict__ pe2,
                     float* __restrict__ PW){
  int layer = blockIdx.x / 3, v = blockIdx.x % 3;
  const float* W  = layer == 0 ? W0 : (layer == 1 ? W1 : W2);
  const float* pe = layer == 0 ? pe0 : (layer == 1 ? pe1 : pe2);
  int K = layer == 0 ? 128 : 256;
  int j = threadIdx.x;
  float s = 0.f;
#pragma unroll
  for (int k = 0; k < POSD; k++)
    s = fmaf(pe[v * POSD + k], W[(size_t)(K + k) * FDIM + j], s);
  PW[(layer * 3 + v) * FDIM + j] = s;
}

// ---------------- features fp32 -> fp16 ----------------
__global__ void f2h_k(const float* __restrict__ in, _Float16* __restrict__ out,
                      int n){
  int i = (blockIdx.x * blockDim.x + threadIdx.x) * 4;
  if (i < n){
    float4 v = *(const float4*)&in[i];
    struct h4s { _Float16 h[4]; } u;
    u.h[0] = (_Float16)v.x; u.h[1] = (_Float16)v.y;
    u.h[2] = (_Float16)v.z; u.h[3] = (_Float16)v.w;
    *(h4s*)&out[i] = u;
  }
}

// ---------------- W fp32 [K][256] -> fp16 transposed Wt[n][K] --------------
__global__ void wcvt_k(const float* __restrict__ W0, const float* __restrict__ W1,
                       const float* __restrict__ W2, _Float16* __restrict__ T0,
                       _Float16* __restrict__ T1, _Float16* __restrict__ T2){
  int l = blockIdx.y;
  const float* W = l == 0 ? W0 : (l == 1 ? W1 : W2);
  _Float16* T    = l == 0 ? T0 : (l == 1 ? T1 : T2);
  int K = l == 0 ? 128 : 256;
  int n = threadIdx.x;   // 0..255
  for (int k = blockIdx.x; k < K; k += gridDim.x)
    T[(size_t)n * K + k] = (_Float16)W[(size_t)k * FDIM + n];
}

// ---------------- MFMA GEMM + fused bias + attention coefficients ----------
__global__ __launch_bounds__(256) void gemm_mfma_k(
    const _Float16* __restrict__ A, const _Float16* __restrict__ Wt,
    const float* __restrict__ PW, const int* __restrict__ pos,
    const float* __restrict__ al, const float* __restrict__ arw,
    _Float16* __restrict__ Ch, float* __restrict__ a1, float* __restrict__ a2,
    int K){
  int t = threadIdx.x;
  int w = t >> 6;
  int lane = t & 63;
  int lm = lane & 15;        // m (A) / n (B) / col (C)
  int kq = lane >> 4;        // quad
  int h = blockIdx.x;
  int rowBase = blockIdx.y * 128 + w * 32;
  int colBase = h * 64;

  floatx4 acc[2][4] = {};

  int r0 = min(rowBase + lm, N_NODES - 1);
  int r1 = min(rowBase + 16 + lm, N_NODES - 1);
  const _Float16* Ar0 = A + (size_t)r0 * K;
  const _Float16* Ar1 = A + (size_t)r1 * K;
  const _Float16* B0 = Wt + (size_t)(colBase + 0 * 16 + lm) * K;
  const _Float16* B1 = Wt + (size_t)(colBase + 1 * 16 + lm) * K;
  const _Float16* B2 = Wt + (size_t)(colBase + 2 * 16 + lm) * K;
  const _Float16* B3 = Wt + (size_t)(colBase + 3 * 16 + lm) * K;

  for (int kb = 0; kb < K; kb += 32){
    int ko = kb + kq * 8;
    half8 a0 = *(const half8*)(Ar0 + ko);
    half8 a1f = *(const half8*)(Ar1 + ko);
    half8 b0 = *(const half8*)(B0 + ko);
    half8 b1 = *(const half8*)(B1 + ko);
    half8 b2 = *(const half8*)(B2 + ko);
    half8 b3 = *(const half8*)(B3 + ko);
    acc[0][0] = __builtin_amdgcn_mfma_f32_16x16x32_f16(a0, b0, acc[0][0], 0, 0, 0);
    acc[0][1] = __builtin_amdgcn_mfma_f32_16x16x32_f16(a0, b1, acc[0][1], 0, 0, 0);
    acc[0][2] = __builtin_amdgcn_mfma_f32_16x16x32_f16(a0, b2, acc[0][2], 0, 0, 0);
    acc[0][3] = __builtin_amdgcn_mfma_f32_16x16x32_f16(a0, b3, acc[0][3], 0, 0, 0);
    acc[1][0] = __builtin_amdgcn_mfma_f32_16x16x32_f16(a1f, b0, acc[1][0], 0, 0, 0);
    acc[1][1] = __builtin_amdgcn_mfma_f32_16x16x32_f16(a1f, b1, acc[1][1], 0, 0, 0);
    acc[1][2] = __builtin_amdgcn_mfma_f32_16x16x32_f16(a1f, b2, acc[1][2], 0, 0, 0);
    acc[1][3] = __builtin_amdgcn_mfma_f32_16x16x32_f16(a1f, b3, acc[1][3], 0, 0, 0);
  }

  float alw[4], arr[4];
#pragma unroll
  for (int j = 0; j < 4; j++){
    alw[j] = al [h * DHEAD + j * 16 + lm];
    arr[j] = arw[h * DHEAD + j * 16 + lm];
  }

#pragma unroll
  for (int i = 0; i < 2; i++){
#pragma unroll
    for (int p = 0; p < 4; p++){
      int row = rowBase + i * 16 + kq * 4 + p;
      if (row >= N_NODES) continue;
      int pz = pos[row];
      const float* pwb = PW + pz * FDIM + colBase;
      float s1 = 0.f, s2 = 0.f;
#pragma unroll
      for (int j = 0; j < 4; j++){
        float v = acc[i][j][p] + pwb[j * 16 + lm];
        Ch[(size_t)row * FDIM + colBase + j * 16 + lm] = (_Float16)v;
        s1 = fmaf(v, alw[j], s1);
        s2 = fmaf(v, arr[j], s2);
      }
      s1 += __shfl_xor(s1, 1, 64); s2 += __shfl_xor(s2, 1, 64);
      s1 += __shfl_xor(s1, 2, 64); s2 += __shfl_xor(s2, 2, 64);
      s1 += __shfl_xor(s1, 4, 64); s2 += __shfl_xor(s2, 4, 64);
      s1 += __shfl_xor(s1, 8, 64); s2 += __shfl_xor(s2, 8, 64);
      if (lm == 0){
        a1[row * HEADS + h] = s1;
        a2[row * HEADS + h] = s2;
      }
    }
  }
}

// ---------------- aggregation: ONE WAVE PER NODE, no LDS, no barriers ------
// lane layout: eidx = lane&15 (edge slot), h = lane>>4 (head) for phase A;
// phase B: lane covers dims [lane*4, lane*4+4) (head = lane>>4).
// Weights for idx >= deg are exactly 0, so phase B chunks need no masking.
__global__ __launch_bounds__(256) void agg4_k(
    const _Float16* __restrict__ ft, const float* __restrict__ a1,
    const float* __restrict__ a2, const int* __restrict__ off,
    const int* __restrict__ esrc, _Float16* __restrict__ outh,
    float* __restrict__ outf, int mode){
  int wv = threadIdx.x >> 6;
  int lane = threadIdx.x & 63;
  int n = blockIdx.x * 4 + wv;
  if (n >= N_NODES) return;
  int jb = off[n];
  int deg = off[n + 1] - jb;
  int eidx = lane & 15, h = lane >> 4;
  int hsel = h << 4;
  float a2n = a2[n * HEADS + h];
  float4 acc = make_float4(0.f, 0.f, 0.f, 0.f);
  const _Float16* ftl = ft + lane * 4;

  if (deg <= 64){
    int sreg[4]; float wreg[4];
    float m = -INFINITY;
#pragma unroll
    for (int r = 0; r < 4; r++){
      int idx = eidx + r * 16;
      int s = (idx < deg) ? esrc[jb + idx] : 0;
      sreg[r] = s;
      float e = (idx < deg) ? lrelu(a1[s * HEADS + h] + a2n) : -INFINITY;
      wreg[r] = e;
      m = fmaxf(m, e);
    }
    m = fmaxf(m, __shfl_xor(m, 1, 64));
    m = fmaxf(m, __shfl_xor(m, 2, 64));
    m = fmaxf(m, __shfl_xor(m, 4, 64));
    m = fmaxf(m, __shfl_xor(m, 8, 64));
    float ss = 0.f;
#pragma unroll
    for (int r = 0; r < 4; r++){
      int idx = eidx + r * 16;
      float t = (idx < deg) ? __expf(wreg[r] - m) : 0.f;
      wreg[r] = t;
      ss += t;
    }
    ss += __shfl_xor(ss, 1, 64);
    ss += __shfl_xor(ss, 2, 64);
    ss += __shfl_xor(ss, 4, 64);
    ss += __shfl_xor(ss, 8, 64);
    float inv = (ss > 0.f) ? 1.f / ss : 0.f;
#pragma unroll
    for (int r = 0; r < 4; r++) wreg[r] *= inv;

    // phase B: unmasked chunks of 4 (weights past deg are 0, sreg=0 is safe)
#pragma unroll
    for (int r = 0; r < 4; r++){
      if (r * 16 >= deg) break;
      int lim = deg - r * 16; if (lim > 16) lim = 16;
      float wr = wreg[r]; int sr = sreg[r];
      for (int jj = 0; jj < lim; jj += 4){
#pragma unroll
        for (int u = 0; u < 4; u++){
          float wj = __shfl(wr, (jj + u) | hsel, 64);
          int sj = __shfl(sr, jj + u, 64);
          struct h4 { __half2 a, b; };
          h4 f = *(const h4*)(ftl + (size_t)sj * FDIM);
          float2 fa = __half22float2(f.a), fb = __half22float2(f.b);
          acc.x = fmaf(wj, fa.x, acc.x);
          acc.y = fmaf(wj, fa.y, acc.y);
          acc.z = fmaf(wj, fb.x, acc.z);
          acc.w = fmaf(wj, fb.y, acc.w);
        }
      }
    }
  } else {
    // generic fallback (deg > 64): correct for any degree, ~never taken
    float m = -INFINITY;
    for (int idx = eidx; idx < deg; idx += 16){
      int s = esrc[jb + idx];
      m = fmaxf(m, lrelu(a1[s * HEADS + h] + a2n));
    }
    m = fmaxf(m, __shfl_xor(m, 1, 64));
    m = fmaxf(m, __shfl_xor(m, 2, 64));
    m = fmaxf(m, __shfl_xor(m, 4, 64));
    m = fmaxf(m, __shfl_xor(m, 8, 64));
    float ss = 0.f;
    for (int idx = eidx; idx < deg; idx += 16){
      int s = esrc[jb + idx];
      ss += __expf(lrelu(a1[s * HEADS + h] + a2n) - m);
    }
    ss += __shfl_xor(ss, 1, 64);
    ss += __shfl_xor(ss, 2, 64);
    ss += __shfl_xor(ss, 4, 64);
    ss += __shfl_xor(ss, 8, 64);
    float inv = (ss > 0.f) ? 1.f / ss : 0.f;
    for (int j = 0; j < deg; j++){
      int sj = esrc[jb + j];
      float e = lrelu(a1[sj * HEADS + h] + a2n);
      float wj = __expf(e - m) * inv;
      struct h4 { __half2 a, b; };
      h4 f = *(const h4*)(ftl + (size_t)sj * FDIM);
      float2 fa = __half22float2(f.a), fb = __half22float2(f.b);
      acc.x = fmaf(wj, fa.x, acc.x);
      acc.y = fmaf(wj, fa.y, acc.y);
      acc.z = fmaf(wj, fb.x, acc.z);
      acc.w = fmaf(wj, fb.y, acc.w);
    }
  }

  if (mode == 0){
    acc.x = acc.x > 0.f ? acc.x : (__expf(acc.x) - 1.f);
    acc.y = acc.y > 0.f ? acc.y : (__expf(acc.y) - 1.f);
    acc.z = acc.z > 0.f ? acc.z : (__expf(acc.z) - 1.f);
    acc.w = acc.w > 0.f ? acc.w : (__expf(acc.w) - 1.f);
    struct h4s { _Float16 h[4]; } u;
    u.h[0] = (_Float16)acc.x; u.h[1] = (_Float16)acc.y;
    u.h[2] = (_Float16)acc.z; u.h[3] = (_Float16)acc.w;
    *(h4s*)&outh[(size_t)n * FDIM + lane * 4] = u;
  } else {
    // head-mean: sum over lanes differing in bits 4,5
#pragma unroll
    for (int o2 = 16; o2 <= 32; o2 <<= 1){
      acc.x += __shfl_xor(acc.x, o2, 64);
      acc.y += __shfl_xor(acc.y, o2, 64);
      acc.z += __shfl_xor(acc.z, o2, 64);
      acc.w += __shfl_xor(acc.w, o2, 64);
    }
    if (lane < 16){
      float4 o;
      o.x = acc.x * 0.25f; o.y = acc.y * 0.25f;
      o.z = acc.z * 0.25f; o.w = acc.w * 0.25f;
      *(float4*)&outf[(size_t)n * DHEAD + lane * 4] = o;
    }
  }
}

// ---------------- launch ----------------
extern "C" void kernel_launch(void* const* d_in, const int* in_sizes, int n_in,
                              void* d_out, int out_size, void* d_ws, size_t ws_size,
                              hipStream_t stream){
  const float* features = (const float*)d_in[0];
  const float* W0  = (const float*)d_in[1];
  const float* al0 = (const float*)d_in[2];
  const float* ar0 = (const float*)d_in[3];
  const float* pe0 = (const float*)d_in[4];
  const float* W1  = (const float*)d_in[5];
  const float* al1 = (const float*)d_in[6];
  const float* ar1 = (const float*)d_in[7];
  const float* pe1 = (const float*)d_in[8];
  const float* W2  = (const float*)d_in[9];
  const float* al2 = (const float*)d_in[10];
  const float* ar2 = (const float*)d_in[11];
  const float* pe2 = (const float*)d_in[12];
  const int* srcv  = (const int*)d_in[13];
  const int* dstv  = (const int*)d_in[14];
  const int* posv  = (const int*)d_in[15];
  float* out = (float*)d_out;

  char* wp = (char*)d_ws;
  auto alloc = [&](size_t bytes){
    void* p = (void*)wp;
    wp += (bytes + 255) & ~(size_t)255;
    return p;
  };
  _Float16* fth   = (_Float16*)alloc(sizeof(_Float16) * (size_t)N_NODES * FDIM);
  _Float16* hbuf  = (_Float16*)alloc(sizeof(_Float16) * (size_t)N_NODES * FDIM);
  _Float16* feat16= (_Float16*)alloc(sizeof(_Float16) * (size_t)N_NODES * 128);
  _Float16* Wt0   = (_Float16*)alloc(sizeof(_Float16) * 256 * 128);
  _Float16* Wt1   = (_Float16*)alloc(sizeof(_Float16) * 256 * 256);
  _Float16* Wt2   = (_Float16*)alloc(sizeof(_Float16) * 256 * 256);
  float* a1     = (float*)alloc(sizeof(float) * N_NODES * HEADS);
  float* a2     = (float*)alloc(sizeof(float) * N_NODES * HEADS);
  float* PW     = (float*)alloc(sizeof(float) * 9 * FDIM);
  int*   deg    = (int*)alloc(sizeof(int) * N_NODES);
  int*   off    = (int*)alloc(sizeof(int) * (N_NODES + 1));
  int*   cursor = (int*)alloc(sizeof(int) * N_NODES);
  int*   bsum   = (int*)alloc(sizeof(int) * 64);
  int*   boff   = (int*)alloc(sizeof(int) * 64);
  int*   esrc   = (int*)alloc(sizeof(int) * N_EDGES);

  // CSR build (graph identical for all 3 layers)
  hipMemsetAsync(deg, 0, sizeof(int) * N_NODES, stream);
  hist_k<<<(N_EDGES + 255) / 256, 256, 0, stream>>>(dstv, deg);
  scanA_k<<<SCAN_NB, SCAN_B, 0, stream>>>(deg, off, bsum);
  scanB_k<<<1, 64, 0, stream>>>(bsum, boff);
  scanC_k<<<SCAN_NB, SCAN_B, 0, stream>>>(off, boff, cursor);
  scatter_k<<<(N_EDGES + 255) / 256, 256, 0, stream>>>(srcv, dstv, cursor, esrc);

  pw_k<<<9, 256, 0, stream>>>(W0, W1, W2, pe0, pe1, pe2, PW);
  f2h_k<<<(N_NODES * 128 / 4 + 255) / 256, 256, 0, stream>>>(
      features, feat16, N_NODES * 128);
  wcvt_k<<<dim3(64, 3), 256, 0, stream>>>(W0, W1, W2, Wt0, Wt1, Wt2);

  dim3 ggrid(HEADS, (N_NODES + 127) / 128);
  int agrid = (N_NODES + 3) / 4;

  // layer 0 (K=128)
  gemm_mfma_k<<<ggrid, 256, 0, stream>>>(feat16, Wt0, PW + 0 * 3 * FDIM, posv,
                                         al0, ar0, fth, a1, a2, 128);
  agg4_k<<<agrid, 256, 0, stream>>>(fth, a1, a2, off, esrc, hbuf, nullptr, 0);

  // layer 1 (K=256)
  gemm_mfma_k<<<ggrid, 256, 0, stream>>>(hbuf, Wt1, PW + 1 * 3 * FDIM, posv,
                                         al1, ar1, fth, a1, a2, 256);
  agg4_k<<<agrid, 256, 0, stream>>>(fth, a1, a2, off, esrc, hbuf, nullptr, 0);

  // layer 2 (K=256, head-mean -> d_out)
  gemm_mfma_k<<<ggrid, 256, 0, stream>>>(hbuf, Wt2, PW + 2 * 3 * FDIM, posv,
                                         al2, ar2, fth, a1, a2, 256);
  agg4_k<<<agrid, 256, 0, stream>>>(fth, a1, a2, off, esrc, nullptr, out, 1);
}